// Round 8
// baseline (121.813 us; speedup 1.0000x reference)
//
#include <hip/hip_runtime.h>
#include <hip/hip_bf16.h>
#include <stdint.h>

#define NBATCH 16
#define NT 2048
#define NC 64
#define SC_LOG2E 11.5415603f  // 8 * log2(e)

typedef __bf16 bf16x8 __attribute__((ext_vector_type(8)));
typedef float f32x4 __attribute__((ext_vector_type(4)));
typedef float f32x16 __attribute__((ext_vector_type(16)));

#define Z16 {0.f,0.f,0.f,0.f,0.f,0.f,0.f,0.f,0.f,0.f,0.f,0.f,0.f,0.f,0.f,0.f}

extern "C" __device__ float __ocml_exp2_f32(float);

static __device__ __forceinline__ unsigned short f2bf(float f) {
  __bf16 h = (__bf16)f;  // hardware RTNE convert
  union { __bf16 h; unsigned short u; } a; a.h = h; return a.u;
}
static __device__ __forceinline__ float bf2f(unsigned short h) {
  union { uint32_t u; float f; } a; a.u = ((uint32_t)h) << 16;
  return a.f;
}
static __device__ __forceinline__ float fasu(uint32_t u) {
  union { uint32_t u; float f; } a; a.u = u; return a.f;
}
static __device__ __forceinline__ uint32_t uasf(float f) {
  union { float f; uint32_t u; } a; a.f = f; return a.u;
}

// ---------------------------------------------------------------------------
// Kernel 1: q,k,v projections. 64 rows per block. (unchanged — known good)
// MFMA with A=W^T (og in reg dim) so k/q stores pack into ushort4.
// Q is pre-scaled by 8*log2(e) so attn softmax is exp2-direct.
// Outputs: khi/klo/qhi/qlo as [B*T][64] bf16 (hi/lo split), vt as [B][64][T].
// ---------------------------------------------------------------------------
__global__ __launch_bounds__(256, 2) void proj_kernel(
    const float* __restrict__ x,
    const float* __restrict__ Wk, const float* __restrict__ bk,
    const float* __restrict__ Wq, const float* __restrict__ bq,
    const float* __restrict__ Wv, const float* __restrict__ bv,
    unsigned short* __restrict__ khi, unsigned short* __restrict__ klo,
    unsigned short* __restrict__ qhi, unsigned short* __restrict__ qlo,
    unsigned short* __restrict__ vt)
{
  __shared__ __align__(16) char smem[65536];
  const int XH = 0, XL = 8192, WTH = 16384, WTL = 40960, VTB = 0; // VTB aliases XH
  const int tid = (int)threadIdx.x;
  const int l = tid & 63, w = tid >> 6;
  const int lr = l & 15, lg = l >> 4;
  const int blk = (int)blockIdx.x;
  const int rowbase = blk * 64;
  const int bb = blk >> 5;          // 32 blocks per batch

  // stage x tile (64x64 f32) as hi/lo bf16, swizzled
  for (int c = tid; c < 1024; c += 256) {
    int row = c >> 4, d0 = (c & 15) * 4;
    const float4 xv = *(const float4*)(x + (size_t)(rowbase + row) * NC + d0);
    unsigned short h0 = f2bf(xv.x), h1 = f2bf(xv.y), h2 = f2bf(xv.z), h3 = f2bf(xv.w);
    unsigned short m0 = f2bf(xv.x - bf2f(h0)), m1 = f2bf(xv.y - bf2f(h1));
    unsigned short m2 = f2bf(xv.z - bf2f(h2)), m3 = f2bf(xv.w - bf2f(h3));
    uint2 ph, pl;
    ph.x = (uint32_t)h0 | ((uint32_t)h1 << 16); ph.y = (uint32_t)h2 | ((uint32_t)h3 << 16);
    pl.x = (uint32_t)m0 | ((uint32_t)m1 << 16); pl.y = (uint32_t)m2 | ((uint32_t)m3 << 16);
    int byteoff = (row * 128 + d0 * 2) ^ ((row & 7) << 4);
    *(uint2*)(smem + XH + byteoff) = ph;
    *(uint2*)(smem + XL + byteoff) = pl;
  }
  // stage W^T (192 og-rows x 64 c-cols) as hi/lo bf16, swizzled
  for (int cw = tid; cw < 3072; cw += 256) {
    int og = cw >> 4, c0 = (cw & 15) * 4;
    const float* Wm = (og < 64) ? Wk : (og < 128 ? Wq : Wv);
    int o = og & 63;
    float w0 = Wm[(size_t)(c0 + 0) * 64 + o];
    float w1 = Wm[(size_t)(c0 + 1) * 64 + o];
    float w2 = Wm[(size_t)(c0 + 2) * 64 + o];
    float w3 = Wm[(size_t)(c0 + 3) * 64 + o];
    unsigned short h0 = f2bf(w0), h1 = f2bf(w1), h2 = f2bf(w2), h3 = f2bf(w3);
    unsigned short m0 = f2bf(w0 - bf2f(h0)), m1 = f2bf(w1 - bf2f(h1));
    unsigned short m2 = f2bf(w2 - bf2f(h2)), m3 = f2bf(w3 - bf2f(h3));
    uint2 ph, pl;
    ph.x = (uint32_t)h0 | ((uint32_t)h1 << 16); ph.y = (uint32_t)h2 | ((uint32_t)h3 << 16);
    pl.x = (uint32_t)m0 | ((uint32_t)m1 << 16); pl.y = (uint32_t)m2 | ((uint32_t)m3 << 16);
    int byteoff = (og * 128 + c0 * 2) ^ ((og & 7) << 4);
    *(uint2*)(smem + WTH + byteoff) = ph;
    *(uint2*)(smem + WTL + byteoff) = pl;
  }
  __syncthreads();

  // x B-frags for this wave's 16 rows (t = w*16 + lr)
  bf16x8 xh[2], xl[2];
  {
    int row = w * 16 + lr;
#pragma unroll
    for (int dc = 0; dc < 2; ++dc) {
      int byteoff = (row * 128 + (dc * 32 + lg * 8) * 2) ^ ((row & 7) << 4);
      xh[dc] = *(const bf16x8*)(smem + XH + byteoff);
      xl[dc] = *(const bf16x8*)(smem + XL + byteoff);
    }
  }
  // A = W^T (rows og -> C reg dim), B = x (rows t -> C lane dim)
  f32x4 acc[12];
#pragma unroll
  for (int nb = 0; nb < 12; ++nb) {
    f32x4 a = {0.f, 0.f, 0.f, 0.f};
    int og = nb * 16 + lr;
#pragma unroll
    for (int dc = 0; dc < 2; ++dc) {
      int byteoff = (og * 128 + (dc * 32 + lg * 8) * 2) ^ ((og & 7) << 4);
      bf16x8 bh = *(const bf16x8*)(smem + WTH + byteoff);
      bf16x8 bl = *(const bf16x8*)(smem + WTL + byteoff);
      a = __builtin_amdgcn_mfma_f32_16x16x32_bf16(bh, xh[dc], a, 0, 0, 0);
      a = __builtin_amdgcn_mfma_f32_16x16x32_bf16(bl, xh[dc], a, 0, 0, 0);
      a = __builtin_amdgcn_mfma_f32_16x16x32_bf16(bh, xl[dc], a, 0, 0, 0);
    }
    acc[nb] = a;
  }
  __syncthreads();  // done reading XH/XL; VTB may now alias

  // epilogue: lane holds t = w*16+lr, og = nb*16 + lg*4 + r (4 consecutive)
  const int tloc = w * 16 + lr;
  const size_t gt = (size_t)(rowbase + tloc);
#pragma unroll
  for (int nb = 0; nb < 12; ++nb) {
    int ogb = (nb & 3) * 16 + lg * 4;
    const float* bp = (nb < 4) ? bk : (nb < 8 ? bq : bv);
    float4 bias = *(const float4*)(bp + ogb);
    float v0 = acc[nb][0] + bias.x, v1 = acc[nb][1] + bias.y,
          v2 = acc[nb][2] + bias.z, v3 = acc[nb][3] + bias.w;
    if (nb < 8) {
      if (nb >= 4) { v0 *= SC_LOG2E; v1 *= SC_LOG2E; v2 *= SC_LOG2E; v3 *= SC_LOG2E; }
      ushort4 hv, lv;
      hv.x = f2bf(v0); lv.x = f2bf(v0 - bf2f(hv.x));
      hv.y = f2bf(v1); lv.y = f2bf(v1 - bf2f(hv.y));
      hv.z = f2bf(v2); lv.z = f2bf(v2 - bf2f(hv.z));
      hv.w = f2bf(v3); lv.w = f2bf(v3 - bf2f(hv.w));
      unsigned short* dH = (nb < 4) ? khi : qhi;
      unsigned short* dL = (nb < 4) ? klo : qlo;
      *(ushort4*)(dH + gt * 64 + ogb) = hv;
      *(ushort4*)(dL + gt * 64 + ogb) = lv;
    } else {
      // v: into LDS transpose buffer [o 64][t 64] bf16, swizzled
      float vs[4] = {v0, v1, v2, v3};
#pragma unroll
      for (int r = 0; r < 4; ++r) {
        int o = ogb + r;
        int byteoff = (o * 128 + tloc * 2) ^ ((o & 7) << 4);
        *(unsigned short*)(smem + VTB + byteoff) = f2bf(vs[r]);
      }
    }
  }
  __syncthreads();
  // copy v^T tile [64 o][64 t] to global [B][64][T]
  for (int cc = tid; cc < 512; cc += 256) {
    int o = cc >> 3, t0 = (cc & 7) * 8;
    int byteoff = (o * 128 + t0 * 2) ^ ((o & 7) << 4);
    uint4 v = *(const uint4*)(smem + VTB + byteoff);
    *(uint4*)(vt + ((size_t)bb * 64 + o) * NT + (size_t)(blk & 31) * 64 + t0) = v;
  }
}

// ---------------------------------------------------------------------------
// Kernel 2: flash attention, barrier-free main loop.
// 256 threads = 4 waves = one 32-row q-group x 4 key-quarters. Grid 1024.
// K/V read global->register (L2-resident); K ping-pong prefetched one iter
// ahead. 3 independent QK^T MFMA chains; permlane32_swap lane exchange.
// LDS + __syncthreads only in the split-K merge epilogue.
// ---------------------------------------------------------------------------
__global__ __launch_bounds__(256, 2) void attn_kernel(
    const unsigned short* __restrict__ khi, const unsigned short* __restrict__ klo,
    const unsigned short* __restrict__ qhi, const unsigned short* __restrict__ qlo,
    const unsigned short* __restrict__ vt,
    float* __restrict__ out)
{
  __shared__ __align__(16) char smem[16896];  // 2 x 8KB O-slots + 512B m/l
  const int MLB = 16384;
  const int tid = (int)threadIdx.x;
  const int l = tid & 63;
  const int cc = tid >> 6;                  // key quarter: keys 32cc..32cc+31
  const int lq = l & 31;
  const bool hi = (l >= 32);
  const int hioff = hi ? 16 : 0;
  // XCD-aware swizzle: 1024 blocks -> 2 whole batches per XCD
  const int lb = ((int)(blockIdx.x & 7) << 7) | ((int)blockIdx.x >> 3);
  const int bb = lb >> 6;
  const int qg = lb & 63;                   // q-group: rows 32qg..32qg+31

  const char* kh_base = (const char*)(khi + (size_t)bb * NT * 64);
  const char* kl_base = (const char*)(klo + (size_t)bb * NT * 64);
  const char* v_base  = (const char*)(vt + (size_t)bb * 64 * NT);

  // --- Q fragments (rows qg*32+lq, B-operand), direct global -> regs
  bf16x8 Qh[4], Ql[4];
  {
    const char* qh_t = (const char*)qhi + ((size_t)bb * NT + (size_t)qg * 32 + lq) * 128 + hioff;
    const char* ql_t = (const char*)qlo + ((size_t)bb * NT + (size_t)qg * 32 + lq) * 128 + hioff;
#pragma unroll
    for (int dc = 0; dc < 4; ++dc) {
      Qh[dc] = *(const bf16x8*)(qh_t + dc * 32);
      Ql[dc] = *(const bf16x8*)(ql_t + dc * 32);
    }
  }

  f32x16 O0 = Z16, O1 = Z16;
  float mrun = -1e30f, lrun = 0.f;

#define LOADK(AH_, AL_, it_)                                                   \
  {                                                                            \
    const char* kt_ = kh_base + (size_t)(it_) * 16384 + cc * 4096 + lq * 128 + hioff; \
    const char* lt_ = kl_base + (size_t)(it_) * 16384 + cc * 4096 + lq * 128 + hioff; \
    AH_[0] = *(const bf16x8*)(kt_);       AH_[1] = *(const bf16x8*)(kt_ + 32); \
    AH_[2] = *(const bf16x8*)(kt_ + 64);  AH_[3] = *(const bf16x8*)(kt_ + 96); \
    AL_[0] = *(const bf16x8*)(lt_);       AL_[1] = *(const bf16x8*)(lt_ + 32); \
    AL_[2] = *(const bf16x8*)(lt_ + 64);  AL_[3] = *(const bf16x8*)(lt_ + 96); \
  }

#define BODY(it_, AH_, AL_, NH_, NL_)                                          \
  {                                                                            \
    /* prefetch next iter's K and this iter's V (independent of MFMAs) */      \
    if ((it_) + 1 < NT / 128) LOADK(NH_, NL_, (it_) + 1);                      \
    bf16x8 va0[2], va1[2];                                                     \
    {                                                                          \
      const char* v0_ = v_base + lq * 4096 + (it_) * 256 + cc * 64 + hioff;    \
      const char* v1_ = v_base + (32 + lq) * 4096 + (it_) * 256 + cc * 64 + hioff; \
      va0[0] = *(const bf16x8*)(v0_);  va0[1] = *(const bf16x8*)(v0_ + 32);    \
      va1[0] = *(const bf16x8*)(v1_);  va1[1] = *(const bf16x8*)(v1_ + 32);    \
    }                                                                          \
    /* S^T[key][q] = K . Q^T, 3 independent chains of depth 4 */               \
    f32x16 T1 = Z16, T2 = Z16, T3 = Z16;                                       \
    __builtin_amdgcn_s_setprio(1);                                             \
    _Pragma("unroll")                                                          \
    for (int dc = 0; dc < 4; ++dc) {                                           \
      T1 = __builtin_amdgcn_mfma_f32_32x32x16_bf16(AH_[dc], Qh[dc], T1, 0, 0, 0); \
      T2 = __builtin_amdgcn_mfma_f32_32x32x16_bf16(AL_[dc], Qh[dc], T2, 0, 0, 0); \
      T3 = __builtin_amdgcn_mfma_f32_32x32x16_bf16(AH_[dc], Ql[dc], T3, 0, 0, 0); \
    }                                                                          \
    __builtin_amdgcn_s_setprio(0);                                             \
    f32x16 S = (T1 + T2) + T3;                                                 \
    /* online softmax in log2 units */                                         \
    float m01 = fmaxf(S[0], S[1]),   m23 = fmaxf(S[2], S[3]);                  \
    float m45 = fmaxf(S[4], S[5]),   m67 = fmaxf(S[6], S[7]);                  \
    float m89 = fmaxf(S[8], S[9]),   mab = fmaxf(S[10], S[11]);                \
    float mcd = fmaxf(S[12], S[13]), mef = fmaxf(S[14], S[15]);                \
    float pmax = fmaxf(fmaxf(fmaxf(m01, m23), fmaxf(m45, m67)),                \
                       fmaxf(fmaxf(m89, mab), fmaxf(mcd, mef)));               \
    {                                                                          \
      auto sw = __builtin_amdgcn_permlane32_swap(uasf(pmax), uasf(pmax), false, false); \
      pmax = fmaxf(fasu(sw[0]), fasu(sw[1]));                                  \
    }                                                                          \
    if (__any(pmax > mrun + 11.55f)) {                                         \
      float mnew = fmaxf(mrun, pmax);                                          \
      float alpha = __ocml_exp2_f32(mrun - mnew);                              \
      O0 *= alpha; O1 *= alpha; lrun *= alpha; mrun = mnew;                    \
    }                                                                          \
    float p[16];                                                               \
    _Pragma("unroll")                                                          \
    for (int i = 0; i < 16; ++i) p[i] = __ocml_exp2_f32(S[i] - mrun);          \
    float s01 = p[0] + p[1],   s23 = p[2] + p[3];                              \
    float s45 = p[4] + p[5],   s67 = p[6] + p[7];                              \
    float s89 = p[8] + p[9],   sab = p[10] + p[11];                            \
    float scd = p[12] + p[13], sef = p[14] + p[15];                            \
    float ts = ((s01 + s23) + (s45 + s67)) + ((s89 + sab) + (scd + sef));      \
    {                                                                          \
      auto sw = __builtin_amdgcn_permlane32_swap(uasf(ts), uasf(ts), false, false); \
      ts = fasu(sw[0]) + fasu(sw[1]);                                          \
    }                                                                          \
    lrun += ts;                                                                \
    /* O^T += V^T . P^T  (A = V^T frags from regs, B = P^T in-register) */     \
    __builtin_amdgcn_s_setprio(1);                                             \
    _Pragma("unroll")                                                          \
    for (int kc = 0; kc < 2; ++kc) {                                           \
      const int b_ = 8 * kc;                                                   \
      uint32_t X0, X1, Y0, Y1;                                                 \
      asm("v_cvt_pk_bf16_f32 %0, %1, %2" : "=v"(X0) : "v"(p[b_+0]), "v"(p[b_+1])); \
      asm("v_cvt_pk_bf16_f32 %0, %1, %2" : "=v"(X1) : "v"(p[b_+2]), "v"(p[b_+3])); \
      asm("v_cvt_pk_bf16_f32 %0, %1, %2" : "=v"(Y0) : "v"(p[b_+4]), "v"(p[b_+5])); \
      asm("v_cvt_pk_bf16_f32 %0, %1, %2" : "=v"(Y1) : "v"(p[b_+6]), "v"(p[b_+7])); \
      auto sw0 = __builtin_amdgcn_permlane32_swap(X0, Y0, false, false);       \
      auto sw1 = __builtin_amdgcn_permlane32_swap(X1, Y1, false, false);       \
      union { uint32_t u[4]; bf16x8 v; } cvb;                                  \
      cvb.u[0] = sw0[0]; cvb.u[1] = sw1[0];                                    \
      cvb.u[2] = sw0[1]; cvb.u[3] = sw1[1];                                    \
      O0 = __builtin_amdgcn_mfma_f32_32x32x16_bf16(va0[kc], cvb.v, O0, 0, 0, 0); \
      O1 = __builtin_amdgcn_mfma_f32_32x32x16_bf16(va1[kc], cvb.v, O1, 0, 0, 0); \
    }                                                                          \
    __builtin_amdgcn_s_setprio(0);                                             \
  }

  // ping-pong K buffers, unroll-2 so all indices are compile-time
  bf16x8 KA[4], LA[4], KB[4], LB[4];
  LOADK(KA, LA, 0);
#pragma unroll 1
  for (int i2 = 0; i2 < NT / 256; ++i2) {
    BODY(2 * i2,     KA, LA, KB, LB)
    BODY(2 * i2 + 1, KB, LB, KA, LA)
  }

  // --- epilogue: 2-stage 4-way split-K merge, then direct f32x4 stores
  const int lsw = (l & 7) << 4;
#define DUMP(idx_)                                                             \
  {                                                                            \
    char* dd = smem + (idx_) * 8192 + l * 128;                                 \
    _Pragma("unroll")                                                          \
    for (int g = 0; g < 4; ++g) {                                              \
      f32x4 t0, t1;                                                            \
      _Pragma("unroll")                                                        \
      for (int j = 0; j < 4; ++j) { t0[j] = O0[4*g+j]; t1[j] = O1[4*g+j]; }    \
      *(f32x4*)(dd + ((g * 16) ^ lsw)) = t0;                                   \
      *(f32x4*)(dd + ((64 + g * 16) ^ lsw)) = t1;                              \
    }                                                                          \
    *(float*)(smem + MLB + (idx_) * 256 + lq * 8) = mrun;                      \
    *(float*)(smem + MLB + (idx_) * 256 + lq * 8 + 4) = lrun;                  \
  }
#define MERGE(idx_)                                                            \
  {                                                                            \
    const char* ds = smem + (idx_) * 8192 + l * 128;                           \
    float m1 = *(const float*)(smem + MLB + (idx_) * 256 + lq * 8);            \
    float l1 = *(const float*)(smem + MLB + (idx_) * 256 + lq * 8 + 4);        \
    float M = fmaxf(mrun, m1);                                                 \
    float a0 = __ocml_exp2_f32(mrun - M);                                      \
    float a1 = __ocml_exp2_f32(m1 - M);                                        \
    lrun = lrun * a0 + l1 * a1;                                                \
    mrun = M;                                                                  \
    _Pragma("unroll")                                                          \
    for (int g = 0; g < 4; ++g) {                                              \
      f32x4 o1a = *(const f32x4*)(ds + ((g * 16) ^ lsw));                      \
      f32x4 o1b = *(const f32x4*)(ds + ((64 + g * 16) ^ lsw));                 \
      _Pragma("unroll")                                                        \
      for (int j = 0; j < 4; ++j) {                                            \
        O0[4*g+j] = O0[4*g+j] * a0 + o1a[j] * a1;                              \
        O1[4*g+j] = O1[4*g+j] * a0 + o1b[j] * a1;                              \
      }                                                                        \
    }                                                                          \
  }
  if (cc & 1) DUMP(cc >> 1);            // cc=1 -> slot 0, cc=3 -> slot 1
  __syncthreads();
  if (!(cc & 1)) MERGE(cc >> 1);        // cc=0 merges 1, cc=2 merges 3
  __syncthreads();
  if (cc == 2) DUMP(1)
  __syncthreads();
  if (cc == 0) {
    MERGE(1)
    float inv = 1.0f / lrun;
    float* orow = out + ((size_t)bb * NT + (size_t)qg * 32 + lq) * 64;
#pragma unroll
    for (int g = 0; g < 4; ++g) {
      int d0 = 8 * g + (hi ? 4 : 0);
      f32x4 s0, s1;
#pragma unroll
      for (int j = 0; j < 4; ++j) { s0[j] = O0[4*g+j] * inv; s1[j] = O1[4*g+j] * inv; }
      *(f32x4*)(orow + d0) = s0;
      *(f32x4*)(orow + d0 + 32) = s1;
    }
  }
#undef DUMP
#undef MERGE
#undef LOADK
#undef BODY
}

extern "C" void kernel_launch(void* const* d_in, const int* in_sizes, int n_in,
                              void* d_out, int out_size, void* d_ws, size_t ws_size,
                              hipStream_t stream) {
  const float* x  = (const float*)d_in[0];
  const float* Wk = (const float*)d_in[1];
  const float* bk = (const float*)d_in[2];
  const float* Wq = (const float*)d_in[3];
  const float* bq = (const float*)d_in[4];
  const float* Wv = (const float*)d_in[5];
  const float* bv = (const float*)d_in[6];
  float* out = (float*)d_out;

  const size_t NE = (size_t)NBATCH * NT * 64;
  unsigned short* ws = (unsigned short*)d_ws;
  unsigned short* khi = ws;
  unsigned short* klo = ws + NE;
  unsigned short* qhi = ws + 2 * NE;
  unsigned short* qlo = ws + 3 * NE;
  unsigned short* vt  = ws + 4 * NE;

  proj_kernel<<<dim3((NBATCH * NT) / 64), dim3(256), 0, stream>>>(
      x, Wk, bk, Wq, bq, Wv, bv, khi, klo, qhi, qlo, vt);
  attn_kernel<<<dim3(NBATCH * 64), dim3(256), 0, stream>>>(
      khi, klo, qhi, qlo, vt, out);
}

// Round 9
// 102.922 us; speedup vs baseline: 1.1835x; 1.1835x over previous
//
#include <hip/hip_runtime.h>
#include <hip/hip_bf16.h>
#include <stdint.h>

#define NBATCH 16
#define NT 2048
#define NC 64
#define QT 128
#define KT 128
#define SC_LOG2E 11.5415603f  // 8 * log2(e)

typedef __bf16 bf16x8 __attribute__((ext_vector_type(8)));
typedef float f32x4 __attribute__((ext_vector_type(4)));
typedef float f32x16 __attribute__((ext_vector_type(16)));

#define Z16 {0.f,0.f,0.f,0.f,0.f,0.f,0.f,0.f,0.f,0.f,0.f,0.f,0.f,0.f,0.f,0.f}

extern "C" __device__ float __ocml_exp2_f32(float);

static __device__ __forceinline__ unsigned short f2bf(float f) {
  __bf16 h = (__bf16)f;  // hardware RTNE convert
  union { __bf16 h; unsigned short u; } a; a.h = h; return a.u;
}
static __device__ __forceinline__ float bf2f(unsigned short h) {
  union { uint32_t u; float f; } a; a.u = ((uint32_t)h) << 16;
  return a.f;
}
static __device__ __forceinline__ float fasu(uint32_t u) {
  union { uint32_t u; float f; } a; a.u = u; return a.f;
}
static __device__ __forceinline__ uint32_t uasf(float f) {
  union { float f; uint32_t u; } a; a.f = f; return a.u;
}
static __device__ __forceinline__ f32x16 zero16() { f32x16 z = Z16; return z; }

#define GLD_LDS16(gsrc, ldst)                                                  \
  __builtin_amdgcn_global_load_lds(                                            \
      (const __attribute__((address_space(1))) void*)(gsrc),                   \
      (__attribute__((address_space(3))) void*)(ldst), 16, 0, 0)

// ---------------------------------------------------------------------------
// Kernel 1: q,k,v projections. 64 rows per block. (unchanged — known good)
// ---------------------------------------------------------------------------
__global__ __launch_bounds__(256, 2) void proj_kernel(
    const float* __restrict__ x,
    const float* __restrict__ Wk, const float* __restrict__ bk,
    const float* __restrict__ Wq, const float* __restrict__ bq,
    const float* __restrict__ Wv, const float* __restrict__ bv,
    unsigned short* __restrict__ khi, unsigned short* __restrict__ klo,
    unsigned short* __restrict__ qhi, unsigned short* __restrict__ qlo,
    unsigned short* __restrict__ vt)
{
  __shared__ __align__(16) char smem[65536];
  const int XH = 0, XL = 8192, WTH = 16384, WTL = 40960, VTB = 0; // VTB aliases XH
  const int tid = (int)threadIdx.x;
  const int l = tid & 63, w = tid >> 6;
  const int lr = l & 15, lg = l >> 4;
  const int blk = (int)blockIdx.x;
  const int rowbase = blk * 64;
  const int bb = blk >> 5;          // 32 blocks per batch

  for (int c = tid; c < 1024; c += 256) {
    int row = c >> 4, d0 = (c & 15) * 4;
    const float4 xv = *(const float4*)(x + (size_t)(rowbase + row) * NC + d0);
    unsigned short h0 = f2bf(xv.x), h1 = f2bf(xv.y), h2 = f2bf(xv.z), h3 = f2bf(xv.w);
    unsigned short m0 = f2bf(xv.x - bf2f(h0)), m1 = f2bf(xv.y - bf2f(h1));
    unsigned short m2 = f2bf(xv.z - bf2f(h2)), m3 = f2bf(xv.w - bf2f(h3));
    uint2 ph, pl;
    ph.x = (uint32_t)h0 | ((uint32_t)h1 << 16); ph.y = (uint32_t)h2 | ((uint32_t)h3 << 16);
    pl.x = (uint32_t)m0 | ((uint32_t)m1 << 16); pl.y = (uint32_t)m2 | ((uint32_t)m3 << 16);
    int byteoff = (row * 128 + d0 * 2) ^ ((row & 7) << 4);
    *(uint2*)(smem + XH + byteoff) = ph;
    *(uint2*)(smem + XL + byteoff) = pl;
  }
  for (int cw = tid; cw < 3072; cw += 256) {
    int og = cw >> 4, c0 = (cw & 15) * 4;
    const float* Wm = (og < 64) ? Wk : (og < 128 ? Wq : Wv);
    int o = og & 63;
    float w0 = Wm[(size_t)(c0 + 0) * 64 + o];
    float w1 = Wm[(size_t)(c0 + 1) * 64 + o];
    float w2 = Wm[(size_t)(c0 + 2) * 64 + o];
    float w3 = Wm[(size_t)(c0 + 3) * 64 + o];
    unsigned short h0 = f2bf(w0), h1 = f2bf(w1), h2 = f2bf(w2), h3 = f2bf(w3);
    unsigned short m0 = f2bf(w0 - bf2f(h0)), m1 = f2bf(w1 - bf2f(h1));
    unsigned short m2 = f2bf(w2 - bf2f(h2)), m3 = f2bf(w3 - bf2f(h3));
    uint2 ph, pl;
    ph.x = (uint32_t)h0 | ((uint32_t)h1 << 16); ph.y = (uint32_t)h2 | ((uint32_t)h3 << 16);
    pl.x = (uint32_t)m0 | ((uint32_t)m1 << 16); pl.y = (uint32_t)m2 | ((uint32_t)m3 << 16);
    int byteoff = (og * 128 + c0 * 2) ^ ((og & 7) << 4);
    *(uint2*)(smem + WTH + byteoff) = ph;
    *(uint2*)(smem + WTL + byteoff) = pl;
  }
  __syncthreads();

  bf16x8 xh[2], xl[2];
  {
    int row = w * 16 + lr;
#pragma unroll
    for (int dc = 0; dc < 2; ++dc) {
      int byteoff = (row * 128 + (dc * 32 + lg * 8) * 2) ^ ((row & 7) << 4);
      xh[dc] = *(const bf16x8*)(smem + XH + byteoff);
      xl[dc] = *(const bf16x8*)(smem + XL + byteoff);
    }
  }
  f32x4 acc[12];
#pragma unroll
  for (int nb = 0; nb < 12; ++nb) {
    f32x4 a = {0.f, 0.f, 0.f, 0.f};
    int og = nb * 16 + lr;
#pragma unroll
    for (int dc = 0; dc < 2; ++dc) {
      int byteoff = (og * 128 + (dc * 32 + lg * 8) * 2) ^ ((og & 7) << 4);
      bf16x8 bh = *(const bf16x8*)(smem + WTH + byteoff);
      bf16x8 bl = *(const bf16x8*)(smem + WTL + byteoff);
      a = __builtin_amdgcn_mfma_f32_16x16x32_bf16(bh, xh[dc], a, 0, 0, 0);
      a = __builtin_amdgcn_mfma_f32_16x16x32_bf16(bl, xh[dc], a, 0, 0, 0);
      a = __builtin_amdgcn_mfma_f32_16x16x32_bf16(bh, xl[dc], a, 0, 0, 0);
    }
    acc[nb] = a;
  }
  __syncthreads();  // done reading XH/XL; VTB may now alias

  const int tloc = w * 16 + lr;
  const size_t gt = (size_t)(rowbase + tloc);
#pragma unroll
  for (int nb = 0; nb < 12; ++nb) {
    int ogb = (nb & 3) * 16 + lg * 4;
    const float* bp = (nb < 4) ? bk : (nb < 8 ? bq : bv);
    float4 bias = *(const float4*)(bp + ogb);
    float v0 = acc[nb][0] + bias.x, v1 = acc[nb][1] + bias.y,
          v2 = acc[nb][2] + bias.z, v3 = acc[nb][3] + bias.w;
    if (nb < 8) {
      if (nb >= 4) { v0 *= SC_LOG2E; v1 *= SC_LOG2E; v2 *= SC_LOG2E; v3 *= SC_LOG2E; }
      ushort4 hv, lv;
      hv.x = f2bf(v0); lv.x = f2bf(v0 - bf2f(hv.x));
      hv.y = f2bf(v1); lv.y = f2bf(v1 - bf2f(hv.y));
      hv.z = f2bf(v2); lv.z = f2bf(v2 - bf2f(hv.z));
      hv.w = f2bf(v3); lv.w = f2bf(v3 - bf2f(hv.w));
      unsigned short* dH = (nb < 4) ? khi : qhi;
      unsigned short* dL = (nb < 4) ? klo : qlo;
      *(ushort4*)(dH + gt * 64 + ogb) = hv;
      *(ushort4*)(dL + gt * 64 + ogb) = lv;
    } else {
      float vs[4] = {v0, v1, v2, v3};
#pragma unroll
      for (int r = 0; r < 4; ++r) {
        int o = ogb + r;
        int byteoff = (o * 128 + tloc * 2) ^ ((o & 7) << 4);
        *(unsigned short*)(smem + VTB + byteoff) = f2bf(vs[r]);
      }
    }
  }
  __syncthreads();
  for (int cc = tid; cc < 512; cc += 256) {
    int o = cc >> 3, t0 = (cc & 7) * 8;
    int byteoff = (o * 128 + t0 * 2) ^ ((o & 7) << 4);
    uint4 v = *(const uint4*)(smem + VTB + byteoff);
    *(uint4*)(vt + ((size_t)bb * 64 + o) * NT + (size_t)(blk & 31) * 64 + t0) = v;
  }
}

// ---------------------------------------------------------------------------
// Kernel 2: flash attention, software-pipelined (deferred softmax).
// 1024 threads = 16 waves = 4 q-groups x 4 key-quarters. Body(i):
// stage(i+1) || QK^T(i)->S_cur (chain result unread) || softmax(S_prev) on
// VALU (overlaps chain) || PV(i-1). K double-buffered, V triple-buffered.
// ---------------------------------------------------------------------------
__global__ __launch_bounds__(1024, 4) void attn_kernel(
    const unsigned short* __restrict__ khi, const unsigned short* __restrict__ klo,
    const unsigned short* __restrict__ qhi, const unsigned short* __restrict__ qlo,
    const unsigned short* __restrict__ vt,
    float* __restrict__ out)
{
  __shared__ __align__(16) char smem[116736];
  const int KB_A = 0, KB_B = 32768;              // each: hi +0, lo +16384
  const int VB_0 = 65536, VB_1 = 81920, VB_2 = 98304;
  const int MLB = 114688;                        // epilogue m/l exchange
  const int tid = (int)threadIdx.x;
  const int l = tid & 63, w = tid >> 6;          // w in 0..15
  const int lq = l & 31;
  const bool hi = (l >= 32);
  const int hioff = hi ? 16 : 0;
  const int r = w & 3;                           // q-group: rows 32r..32r+31
  const int cc = w >> 2;                         // key quarter
  const int lb = ((int)(blockIdx.x & 7) << 5) | ((int)blockIdx.x >> 3);
  const int bb = lb >> 4;
  const int qt = lb & 15;

  const char* kh_base = (const char*)(khi + (size_t)bb * NT * 64);
  const char* kl_base = (const char*)(klo + (size_t)bb * NT * 64);
  const char* v_base  = (const char*)(vt + (size_t)bb * 64 * NT);

#define STAGE(it_, kb_, vb_)                                                   \
  do {                                                                         \
    const char* kh_t = kh_base + (size_t)(it_) * 16384;                        \
    const char* kl_t = kl_base + (size_t)(it_) * 16384;                        \
    const char* v_tb = v_base + (size_t)(it_) * 256;                           \
    int d_ = w * 1024 + l * 16;                                                \
    int swk_ = d_ ^ (((d_ >> 7) & 7) << 4);                                    \
    GLD_LDS16(kh_t + swk_, smem + (kb_) + w * 1024);                           \
    GLD_LDS16(kl_t + swk_, smem + (kb_) + 16384 + w * 1024);                   \
    int o_ = d_ >> 8;                                                          \
    int swv_ = (d_ & 255) ^ ((o_ & 7) << 4);                                   \
    GLD_LDS16(v_tb + (size_t)o_ * 4096 + swv_, smem + (vb_) + w * 1024);       \
  } while (0)

  const int swr = (lq & 7) << 4;

  // prologue: stage tiles 0,1; Q fragments to regs
  STAGE(0, KB_A, VB_0);
  STAGE(1, KB_B, VB_1);
  bf16x8 Qh[4], Ql[4];
  {
    const char* qh_t = (const char*)qhi + ((size_t)bb * NT + (size_t)qt * QT) * 128;
    const char* ql_t = (const char*)qlo + ((size_t)bb * NT + (size_t)qt * QT) * 128;
    int qrow = r * 32 + lq;
#pragma unroll
    for (int dc = 0; dc < 4; ++dc) {
      Qh[dc] = *(const bf16x8*)(qh_t + qrow * 128 + dc * 32 + hioff);
      Ql[dc] = *(const bf16x8*)(ql_t + qrow * 128 + dc * 32 + hioff);
    }
  }
  asm volatile("s_waitcnt vmcnt(0)" ::: "memory");
  __builtin_amdgcn_s_barrier();
  asm volatile("" ::: "memory");

  // QK^T for one tile from K buffer kb_ into accumulator SDST (depth-12 chain)
#define QK_CHAIN(kb_, SDST)                                                    \
  {                                                                            \
    int krow_ = cc * 32 + lq;                                                  \
    __builtin_amdgcn_s_setprio(1);                                             \
    _Pragma("unroll")                                                          \
    for (int dc = 0; dc < 4; ++dc) {                                           \
      int cchunk_ = (dc * 32 + hioff) ^ swr;                                   \
      bf16x8 Ah_ = *(const bf16x8*)(smem + (kb_) + krow_ * 128 + cchunk_);     \
      bf16x8 Al_ = *(const bf16x8*)(smem + (kb_) + 16384 + krow_ * 128 + cchunk_); \
      SDST = __builtin_amdgcn_mfma_f32_32x32x16_bf16(Ah_, Qh[dc], SDST, 0, 0, 0); \
      SDST = __builtin_amdgcn_mfma_f32_32x32x16_bf16(Al_, Qh[dc], SDST, 0, 0, 0); \
      SDST = __builtin_amdgcn_mfma_f32_32x32x16_bf16(Ah_, Ql[dc], SDST, 0, 0, 0); \
    }                                                                          \
    __builtin_amdgcn_s_setprio(0);                                             \
  }

  // softmax of SP_ (a completed S tile) + PV from V buffer vb_
#define SMPV(SP_, vb_)                                                         \
  {                                                                            \
    float m01 = fmaxf(SP_[0], SP_[1]),   m23 = fmaxf(SP_[2], SP_[3]);          \
    float m45 = fmaxf(SP_[4], SP_[5]),   m67 = fmaxf(SP_[6], SP_[7]);          \
    float m89 = fmaxf(SP_[8], SP_[9]),   mab = fmaxf(SP_[10], SP_[11]);        \
    float mcd = fmaxf(SP_[12], SP_[13]), mef = fmaxf(SP_[14], SP_[15]);        \
    float pmax = fmaxf(fmaxf(fmaxf(m01, m23), fmaxf(m45, m67)),                \
                       fmaxf(fmaxf(m89, mab), fmaxf(mcd, mef)));               \
    {                                                                          \
      auto sw_ = __builtin_amdgcn_permlane32_swap(uasf(pmax), uasf(pmax), false, false); \
      pmax = fmaxf(fasu(sw_[0]), fasu(sw_[1]));                                \
    }                                                                          \
    if (__any(pmax > mrun + 11.55f)) {                                         \
      float mnew = fmaxf(mrun, pmax);                                          \
      float alpha = __ocml_exp2_f32(mrun - mnew);                              \
      O0 *= alpha; O1 *= alpha; lrun *= alpha; mrun = mnew;                    \
    }                                                                          \
    float p[16];                                                               \
    _Pragma("unroll")                                                          \
    for (int i = 0; i < 16; ++i) p[i] = __ocml_exp2_f32(SP_[i] - mrun);        \
    float s01 = p[0] + p[1],   s23 = p[2] + p[3];                              \
    float s45 = p[4] + p[5],   s67 = p[6] + p[7];                              \
    float s89 = p[8] + p[9],   sab = p[10] + p[11];                            \
    float scd = p[12] + p[13], sef = p[14] + p[15];                            \
    float ts = ((s01 + s23) + (s45 + s67)) + ((s89 + sab) + (scd + sef));      \
    {                                                                          \
      auto sw_ = __builtin_amdgcn_permlane32_swap(uasf(ts), uasf(ts), false, false); \
      ts = fasu(sw_[0]) + fasu(sw_[1]);                                        \
    }                                                                          \
    lrun += ts;                                                                \
    __builtin_amdgcn_s_setprio(1);                                             \
    _Pragma("unroll")                                                          \
    for (int kc = 0; kc < 2; ++kc) {                                           \
      const int b_ = 8 * kc;                                                   \
      uint32_t X0, X1, Y0, Y1;                                                 \
      asm("v_cvt_pk_bf16_f32 %0, %1, %2" : "=v"(X0) : "v"(p[b_+0]), "v"(p[b_+1])); \
      asm("v_cvt_pk_bf16_f32 %0, %1, %2" : "=v"(X1) : "v"(p[b_+2]), "v"(p[b_+3])); \
      asm("v_cvt_pk_bf16_f32 %0, %1, %2" : "=v"(Y0) : "v"(p[b_+4]), "v"(p[b_+5])); \
      asm("v_cvt_pk_bf16_f32 %0, %1, %2" : "=v"(Y1) : "v"(p[b_+6]), "v"(p[b_+7])); \
      auto sw0_ = __builtin_amdgcn_permlane32_swap(X0, Y0, false, false);      \
      auto sw1_ = __builtin_amdgcn_permlane32_swap(X1, Y1, false, false);      \
      union { uint32_t u[4]; bf16x8 v; } cvb_;                                 \
      cvb_.u[0] = sw0_[0]; cvb_.u[1] = sw1_[0];                                \
      cvb_.u[2] = sw0_[1]; cvb_.u[3] = sw1_[1];                                \
      int vcol_ = 64 * cc + 32 * kc + hioff;                                   \
      bf16x8 Av0_ = *(const bf16x8*)(smem + (vb_) + lq * 256 + (vcol_ ^ swr)); \
      bf16x8 Av1_ = *(const bf16x8*)(smem + (vb_) + (32 + lq) * 256 + (vcol_ ^ swr)); \
      O0 = __builtin_amdgcn_mfma_f32_32x32x16_bf16(Av0_, cvb_.v, O0, 0, 0, 0); \
      O1 = __builtin_amdgcn_mfma_f32_32x32x16_bf16(Av1_, cvb_.v, O1, 0, 0, 0); \
    }                                                                          \
    __builtin_amdgcn_s_setprio(0);                                             \
  }

  f32x16 O0 = zero16(), O1 = zero16();
  float mrun = -1e30f, lrun = 0.f;

  // QK(0) -> SA; barrier so body(1)'s stage of tile 2 can reuse KB_A
  f32x16 SA = zero16(), SB = zero16();
  QK_CHAIN(KB_A, SA);
  asm volatile("s_waitcnt lgkmcnt(0)" ::: "memory");
  __builtin_amdgcn_s_barrier();
  asm volatile("" ::: "memory");

  int kbC = KB_B, kbN = KB_A;
  int vbP = VB_0, vbC = VB_1, vbN = VB_2;

#define BODY(i_, SP_, SC_, DOSTAGE_)                                           \
  {                                                                            \
    if (DOSTAGE_) STAGE((i_) + 1, kbN, vbN);                                   \
    SC_ = zero16();                                                            \
    QK_CHAIN(kbC, SC_);                                                        \
    SMPV(SP_, vbP);                                                            \
    asm volatile("s_waitcnt vmcnt(0)" ::: "memory");                           \
    __builtin_amdgcn_s_barrier();                                              \
    asm volatile("" ::: "memory");                                             \
  }
#define ROT()                                                                  \
  { int t_ = vbP; vbP = vbC; vbC = vbN; vbN = t_;                              \
    t_ = kbC; kbC = kbN; kbN = t_; }

#pragma unroll 1
  for (int ib = 0; ib < 7; ++ib) {
    BODY(2 * ib + 1, SA, SB, 1)
    ROT()
    BODY(2 * ib + 2, SB, SA, 1)
    ROT()
  }
  BODY(15, SA, SB, 0)
  // tail: softmax + PV for tile 15 (V(15) lives in vbC; no rotation done)
  SMPV(SB, vbC);

  // --- epilogue: 2-stage 4-way split-K merge (slots alias K buffers)
  const int lsw = (l & 7) << 4;
#define DUMP(idx_)                                                             \
  {                                                                            \
    char* dd = smem + (idx_) * 8192 + l * 128;                                 \
    _Pragma("unroll")                                                          \
    for (int g = 0; g < 4; ++g) {                                              \
      f32x4 t0, t1;                                                            \
      _Pragma("unroll")                                                        \
      for (int j = 0; j < 4; ++j) { t0[j] = O0[4*g+j]; t1[j] = O1[4*g+j]; }    \
      *(f32x4*)(dd + ((g * 16) ^ lsw)) = t0;                                   \
      *(f32x4*)(dd + ((64 + g * 16) ^ lsw)) = t1;                              \
    }                                                                          \
    *(float*)(smem + MLB + (idx_) * 256 + lq * 8) = mrun;                      \
    *(float*)(smem + MLB + (idx_) * 256 + lq * 8 + 4) = lrun;                  \
  }
#define MERGE(idx_)                                                            \
  {                                                                            \
    const char* ds = smem + (idx_) * 8192 + l * 128;                           \
    float m1 = *(const float*)(smem + MLB + (idx_) * 256 + lq * 8);            \
    float l1 = *(const float*)(smem + MLB + (idx_) * 256 + lq * 8 + 4);        \
    float M = fmaxf(mrun, m1);                                                 \
    float a0 = __ocml_exp2_f32(mrun - M);                                      \
    float a1 = __ocml_exp2_f32(m1 - M);                                        \
    lrun = lrun * a0 + l1 * a1;                                                \
    mrun = M;                                                                  \
    _Pragma("unroll")                                                          \
    for (int g = 0; g < 4; ++g) {                                              \
      f32x4 o1a = *(const f32x4*)(ds + ((g * 16) ^ lsw));                      \
      f32x4 o1b = *(const f32x4*)(ds + ((64 + g * 16) ^ lsw));                 \
      _Pragma("unroll")                                                        \
      for (int j = 0; j < 4; ++j) {                                            \
        O0[4*g+j] = O0[4*g+j] * a0 + o1a[j] * a1;                              \
        O1[4*g+j] = O1[4*g+j] * a0 + o1b[j] * a1;                              \
      }                                                                        \
    }                                                                          \
  }
  if (cc & 1) DUMP(r * 2 + (cc >> 1));      // cc=1 -> idx 2r, cc=3 -> idx 2r+1
  __syncthreads();
  if (!(cc & 1)) MERGE(r * 2 + (cc >> 1));  // cc=0 takes cc=1, cc=2 takes cc=3
  __syncthreads();
  if (cc == 2) DUMP(r * 2 + 1);
  __syncthreads();
  if (cc == 0) {
    MERGE(r * 2 + 1);
    float inv = 1.0f / lrun;
    float* orow = out + ((size_t)bb * NT + (size_t)qt * QT + r * 32 + lq) * 64;
#pragma unroll
    for (int g = 0; g < 4; ++g) {
      int d0 = 8 * g + (hi ? 4 : 0);
      f32x4 s0, s1;
#pragma unroll
      for (int j = 0; j < 4; ++j) { s0[j] = O0[4*g+j] * inv; s1[j] = O1[4*g+j] * inv; }
      *(f32x4*)(orow + d0) = s0;
      *(f32x4*)(orow + d0 + 32) = s1;
    }
  }
#undef DUMP
#undef MERGE
#undef BODY
#undef ROT
#undef SMPV
#undef QK_CHAIN
#undef STAGE
}

extern "C" void kernel_launch(void* const* d_in, const int* in_sizes, int n_in,
                              void* d_out, int out_size, void* d_ws, size_t ws_size,
                              hipStream_t stream) {
  const float* x  = (const float*)d_in[0];
  const float* Wk = (const float*)d_in[1];
  const float* bk = (const float*)d_in[2];
  const float* Wq = (const float*)d_in[3];
  const float* bq = (const float*)d_in[4];
  const float* Wv = (const float*)d_in[5];
  const float* bv = (const float*)d_in[6];
  float* out = (float*)d_out;

  const size_t NE = (size_t)NBATCH * NT * 64;
  unsigned short* ws = (unsigned short*)d_ws;
  unsigned short* khi = ws;
  unsigned short* klo = ws + NE;
  unsigned short* qhi = ws + 2 * NE;
  unsigned short* qlo = ws + 3 * NE;
  unsigned short* vt  = ws + 4 * NE;

  proj_kernel<<<dim3((NBATCH * NT) / 64), dim3(256), 0, stream>>>(
      x, Wk, bk, Wq, bq, Wv, bv, khi, klo, qhi, qlo, vt);
  attn_kernel<<<dim3(NBATCH * (NT / QT)), dim3(1024), 0, stream>>>(
      khi, klo, qhi, qlo, vt, out);
}

// Round 10
// 72.785 us; speedup vs baseline: 1.6736x; 1.4141x over previous
//
#include <hip/hip_runtime.h>
#include <hip/hip_bf16.h>
#include <stdint.h>

#define NBATCH 16
#define NT 2048
#define NC 64
#define QT 128
#define KT 128
#define SC_LOG2E 11.5415603f  // 8 * log2(e)

typedef __bf16 bf16x8 __attribute__((ext_vector_type(8)));
typedef float f32x4 __attribute__((ext_vector_type(4)));
typedef float f32x16 __attribute__((ext_vector_type(16)));

#define Z16 {0.f,0.f,0.f,0.f,0.f,0.f,0.f,0.f,0.f,0.f,0.f,0.f,0.f,0.f,0.f,0.f}

extern "C" __device__ float __ocml_exp2_f32(float);

static __device__ __forceinline__ unsigned short f2bf(float f) {
  __bf16 h = (__bf16)f;  // hardware RTNE convert
  union { __bf16 h; unsigned short u; } a; a.h = h; return a.u;
}
static __device__ __forceinline__ float bf2f(unsigned short h) {
  union { uint32_t u; float f; } a; a.u = ((uint32_t)h) << 16;
  return a.f;
}
static __device__ __forceinline__ float fasu(uint32_t u) {
  union { uint32_t u; float f; } a; a.u = u; return a.f;
}
static __device__ __forceinline__ uint32_t uasf(float f) {
  union { float f; uint32_t u; } a; a.f = f; return a.u;
}

#define GLD_LDS16(gsrc, ldst)                                                  \
  __builtin_amdgcn_global_load_lds(                                            \
      (const __attribute__((address_space(1))) void*)(gsrc),                   \
      (__attribute__((address_space(3))) void*)(ldst), 16, 0, 0)

// ---------------------------------------------------------------------------
// Kernel 0: one-time W transpose + hi/lo bf16 split. 3 blocks (k,q,v).
// In: W[c][o] f32 row-major. Out: wt_hi/wt_lo[og][c] bf16, og = m*64+o.
// ---------------------------------------------------------------------------
__global__ __launch_bounds__(256, 2) void prep_w(
    const float* __restrict__ Wk, const float* __restrict__ Wq,
    const float* __restrict__ Wv,
    unsigned short* __restrict__ wt_hi, unsigned short* __restrict__ wt_lo)
{
  __shared__ unsigned short hbuf[64][66];   // +2 pad: bank-conflict-free transpose
  __shared__ unsigned short lbuf[64][66];
  const int m = (int)blockIdx.x;
  const float* Wm = (m == 0) ? Wk : (m == 1 ? Wq : Wv);
  const int tid = (int)threadIdx.x;
  for (int idx = tid; idx < 1024; idx += 256) {
    int c = idx >> 4, o4 = (idx & 15) * 4;
    float4 v = *(const float4*)(Wm + c * 64 + o4);
    float vals[4] = {v.x, v.y, v.z, v.w};
#pragma unroll
    for (int j = 0; j < 4; ++j) {
      unsigned short h = f2bf(vals[j]);
      hbuf[o4 + j][c] = h;
      lbuf[o4 + j][c] = f2bf(vals[j] - bf2f(h));
    }
  }
  __syncthreads();
  for (int idx = tid; idx < 1024; idx += 256) {
    int o = idx >> 4, c0 = (idx & 15) * 4;
    ushort4 hv, lv;
    hv.x = hbuf[o][c0]; hv.y = hbuf[o][c0 + 1];
    hv.z = hbuf[o][c0 + 2]; hv.w = hbuf[o][c0 + 3];
    lv.x = lbuf[o][c0]; lv.y = lbuf[o][c0 + 1];
    lv.z = lbuf[o][c0 + 2]; lv.w = lbuf[o][c0 + 3];
    *(ushort4*)(wt_hi + (size_t)(m * 64 + o) * 64 + c0) = hv;
    *(ushort4*)(wt_lo + (size_t)(m * 64 + o) * 64 + c0) = lv;
  }
}

// ---------------------------------------------------------------------------
// Kernel 1: q,k,v projections. 64 rows per block. W^T now staged via
// global_load_lds from preconverted wt_hi/wt_lo (coalesced, zero VALU).
// Q pre-scaled by 8*log2(e). Outputs: khi/klo/qhi/qlo [B*T][64], vt [B][64][T].
// ---------------------------------------------------------------------------
__global__ __launch_bounds__(256, 2) void proj_kernel(
    const float* __restrict__ x,
    const unsigned short* __restrict__ wt_hi, const unsigned short* __restrict__ wt_lo,
    const float* __restrict__ bk, const float* __restrict__ bq, const float* __restrict__ bv,
    unsigned short* __restrict__ khi, unsigned short* __restrict__ klo,
    unsigned short* __restrict__ qhi, unsigned short* __restrict__ qlo,
    unsigned short* __restrict__ vt)
{
  __shared__ __align__(16) char smem[65536];
  const int XH = 0, XL = 8192, WTH = 16384, WTL = 40960, VTB = 0; // VTB aliases XH
  const int tid = (int)threadIdx.x;
  const int l = tid & 63, w = tid >> 6;
  const int lr = l & 15, lg = l >> 4;
  const int blk = (int)blockIdx.x;
  const int rowbase = blk * 64;
  const int bb = blk >> 5;          // 32 blocks per batch

  // stage W^T hi/lo (24 KB each) via global_load_lds, pre-swizzled source
#pragma unroll
  for (int ch4 = 0; ch4 < 6; ++ch4) {
    int ch = ch4 * 4 + w;           // 24 chunks of 1KB per region
    int d = ch * 1024 + l * 16;
    int swk = d ^ (((d >> 7) & 7) << 4);
    GLD_LDS16((const char*)wt_hi + swk, smem + WTH + ch * 1024);
    GLD_LDS16((const char*)wt_lo + swk, smem + WTL + ch * 1024);
  }
  // stage x tile (64x64 f32) as hi/lo bf16, swizzled
  for (int c = tid; c < 1024; c += 256) {
    int row = c >> 4, d0 = (c & 15) * 4;
    const float4 xv = *(const float4*)(x + (size_t)(rowbase + row) * NC + d0);
    unsigned short h0 = f2bf(xv.x), h1 = f2bf(xv.y), h2 = f2bf(xv.z), h3 = f2bf(xv.w);
    unsigned short m0 = f2bf(xv.x - bf2f(h0)), m1 = f2bf(xv.y - bf2f(h1));
    unsigned short m2 = f2bf(xv.z - bf2f(h2)), m3 = f2bf(xv.w - bf2f(h3));
    uint2 ph, pl;
    ph.x = (uint32_t)h0 | ((uint32_t)h1 << 16); ph.y = (uint32_t)h2 | ((uint32_t)h3 << 16);
    pl.x = (uint32_t)m0 | ((uint32_t)m1 << 16); pl.y = (uint32_t)m2 | ((uint32_t)m3 << 16);
    int byteoff = (row * 128 + d0 * 2) ^ ((row & 7) << 4);
    *(uint2*)(smem + XH + byteoff) = ph;
    *(uint2*)(smem + XL + byteoff) = pl;
  }
  __syncthreads();

  // x B-frags for this wave's 16 rows (t = w*16 + lr)
  bf16x8 xh[2], xl[2];
  {
    int row = w * 16 + lr;
#pragma unroll
    for (int dc = 0; dc < 2; ++dc) {
      int byteoff = (row * 128 + (dc * 32 + lg * 8) * 2) ^ ((row & 7) << 4);
      xh[dc] = *(const bf16x8*)(smem + XH + byteoff);
      xl[dc] = *(const bf16x8*)(smem + XL + byteoff);
    }
  }
  // A = W^T (rows og -> C reg dim), B = x (rows t -> C lane dim)
  f32x4 acc[12];
#pragma unroll
  for (int nb = 0; nb < 12; ++nb) {
    f32x4 a = {0.f, 0.f, 0.f, 0.f};
    int og = nb * 16 + lr;
#pragma unroll
    for (int dc = 0; dc < 2; ++dc) {
      int byteoff = (og * 128 + (dc * 32 + lg * 8) * 2) ^ ((og & 7) << 4);
      bf16x8 bh = *(const bf16x8*)(smem + WTH + byteoff);
      bf16x8 bl = *(const bf16x8*)(smem + WTL + byteoff);
      a = __builtin_amdgcn_mfma_f32_16x16x32_bf16(bh, xh[dc], a, 0, 0, 0);
      a = __builtin_amdgcn_mfma_f32_16x16x32_bf16(bl, xh[dc], a, 0, 0, 0);
      a = __builtin_amdgcn_mfma_f32_16x16x32_bf16(bh, xl[dc], a, 0, 0, 0);
    }
    acc[nb] = a;
  }
  __syncthreads();  // done reading XH/XL; VTB may now alias

  // epilogue: lane holds t = w*16+lr, og = nb*16 + lg*4 + r (4 consecutive)
  const int tloc = w * 16 + lr;
  const size_t gt = (size_t)(rowbase + tloc);
#pragma unroll
  for (int nb = 0; nb < 12; ++nb) {
    int ogb = (nb & 3) * 16 + lg * 4;
    const float* bp = (nb < 4) ? bk : (nb < 8 ? bq : bv);
    float4 bias = *(const float4*)(bp + ogb);
    float v0 = acc[nb][0] + bias.x, v1 = acc[nb][1] + bias.y,
          v2 = acc[nb][2] + bias.z, v3 = acc[nb][3] + bias.w;
    if (nb < 8) {
      if (nb >= 4) { v0 *= SC_LOG2E; v1 *= SC_LOG2E; v2 *= SC_LOG2E; v3 *= SC_LOG2E; }
      ushort4 hv, lv;
      hv.x = f2bf(v0); lv.x = f2bf(v0 - bf2f(hv.x));
      hv.y = f2bf(v1); lv.y = f2bf(v1 - bf2f(hv.y));
      hv.z = f2bf(v2); lv.z = f2bf(v2 - bf2f(hv.z));
      hv.w = f2bf(v3); lv.w = f2bf(v3 - bf2f(hv.w));
      unsigned short* dH = (nb < 4) ? khi : qhi;
      unsigned short* dL = (nb < 4) ? klo : qlo;
      *(ushort4*)(dH + gt * 64 + ogb) = hv;
      *(ushort4*)(dL + gt * 64 + ogb) = lv;
    } else {
      // v: into LDS transpose buffer [o 64][t 64] bf16, swizzled
      float vs[4] = {v0, v1, v2, v3};
#pragma unroll
      for (int r = 0; r < 4; ++r) {
        int o = ogb + r;
        int byteoff = (o * 128 + tloc * 2) ^ ((o & 7) << 4);
        *(unsigned short*)(smem + VTB + byteoff) = f2bf(vs[r]);
      }
    }
  }
  __syncthreads();
  // copy v^T tile [64 o][64 t] to global [B][64][T]
  for (int cc = tid; cc < 512; cc += 256) {
    int o = cc >> 3, t0 = (cc & 7) * 8;
    int byteoff = (o * 128 + t0 * 2) ^ ((o & 7) << 4);
    uint4 v = *(const uint4*)(smem + VTB + byteoff);
    *(uint4*)(vt + ((size_t)bb * 64 + o) * NT + (size_t)(blk & 31) * 64 + t0) = v;
  }
}

// ---------------------------------------------------------------------------
// Kernel 2: flash attention — round-5 structure (validated 55.6 us) with the
// shfl_xor(32) sites replaced by permlane32_swap (validated in round 7).
// 1024 threads = 16 waves = 4 q-groups x 4 key-quarters. Single S chain.
// ---------------------------------------------------------------------------
__global__ __launch_bounds__(1024, 4) void attn_kernel(
    const unsigned short* __restrict__ khi, const unsigned short* __restrict__ klo,
    const unsigned short* __restrict__ qhi, const unsigned short* __restrict__ qlo,
    const unsigned short* __restrict__ vt,
    float* __restrict__ out)
{
  __shared__ __align__(16) char smem[98304];
  const int BUF = 49152;   // per-buffer: KHI 16K | KLO 16K | VT 16K
  const int MLB = 65536;   // epilogue m/l exchange (aliases buf space)
  const int tid = (int)threadIdx.x;
  const int l = tid & 63, w = tid >> 6;     // w in 0..15
  const int lq = l & 31;
  const bool hi = (l >= 32);
  const int hioff = hi ? 16 : 0;
  const int r = w & 3;                      // q-group: rows 32r..32r+31
  const int cc = w >> 2;                    // key quarter: keys 32cc..32cc+31
  const int lb = ((int)(blockIdx.x & 7) << 5) | ((int)blockIdx.x >> 3);
  const int bb = lb >> 4;
  const int qt = lb & 15;

  const char* kh_base = (const char*)(khi + (size_t)bb * NT * 64);
  const char* kl_base = (const char*)(klo + (size_t)bb * NT * 64);
  const char* v_base  = (const char*)(vt + (size_t)bb * 64 * NT);

#define STAGE_TILE(bufp_, it_)                                                 \
  do {                                                                         \
    const char* kh_t = kh_base + (size_t)(it_) * 16384;                        \
    const char* kl_t = kl_base + (size_t)(it_) * 16384;                        \
    const char* v_tb = v_base + (size_t)(it_) * 256;                           \
    int d_ = w * 1024 + l * 16;                                                \
    int swk_ = d_ ^ (((d_ >> 7) & 7) << 4);                                    \
    GLD_LDS16(kh_t + swk_, (bufp_) + w * 1024);                                \
    GLD_LDS16(kl_t + swk_, (bufp_) + 16384 + w * 1024);                        \
    int o_ = d_ >> 8;                                                          \
    int swv_ = (d_ & 255) ^ ((o_ & 7) << 4);                                   \
    GLD_LDS16(v_tb + (size_t)o_ * 4096 + swv_, (bufp_) + 32768 + w * 1024);    \
  } while (0)

  // prologue: stage tile 0; load Q fragments (rows 32r..32r+31, B-operand)
  STAGE_TILE(smem, 0);
  bf16x8 Qh[4], Ql[4];
  {
    const char* qh_t = (const char*)qhi + ((size_t)bb * NT + (size_t)qt * QT) * 128;
    const char* ql_t = (const char*)qlo + ((size_t)bb * NT + (size_t)qt * QT) * 128;
    int qrow = r * 32 + lq;
#pragma unroll
    for (int dc = 0; dc < 4; ++dc) {
      Qh[dc] = *(const bf16x8*)(qh_t + qrow * 128 + dc * 32 + hioff);
      Ql[dc] = *(const bf16x8*)(ql_t + qrow * 128 + dc * 32 + hioff);
    }
  }
  asm volatile("s_waitcnt vmcnt(0)" ::: "memory");
  __builtin_amdgcn_s_barrier();
  asm volatile("" ::: "memory");

  f32x16 O0 = Z16, O1 = Z16;
  float mrun = -1e30f, lrun = 0.f;
  const int swr = (lq & 7) << 4;

  for (int it = 0; it < NT / KT; ++it) {
    char* cb = smem + (it & 1) * BUF;
    if (it + 1 < NT / KT) STAGE_TILE(smem + ((it + 1) & 1) * BUF, it + 1);

    // --- S^T[key][q] = K · Q^T (3-term hi/lo), single accumulator chain
    f32x16 S = Z16;
    __builtin_amdgcn_s_setprio(1);
#pragma unroll
    for (int dc = 0; dc < 4; ++dc) {
      int krow = cc * 32 + lq;
      int cchunk = (dc * 32 + hioff) ^ swr;
      bf16x8 Ah = *(const bf16x8*)(cb + krow * 128 + cchunk);
      bf16x8 Al = *(const bf16x8*)(cb + 16384 + krow * 128 + cchunk);
      S = __builtin_amdgcn_mfma_f32_32x32x16_bf16(Ah, Qh[dc], S, 0, 0, 0);
      S = __builtin_amdgcn_mfma_f32_32x32x16_bf16(Al, Qh[dc], S, 0, 0, 0);
      S = __builtin_amdgcn_mfma_f32_32x32x16_bf16(Ah, Ql[dc], S, 0, 0, 0);
    }
    __builtin_amdgcn_s_setprio(0);

    // --- online softmax in log2 units; tree + permlane cross-half reduce
    float m01 = fmaxf(S[0], S[1]),   m23 = fmaxf(S[2], S[3]);
    float m45 = fmaxf(S[4], S[5]),   m67 = fmaxf(S[6], S[7]);
    float m89 = fmaxf(S[8], S[9]),   mab = fmaxf(S[10], S[11]);
    float mcd = fmaxf(S[12], S[13]), mef = fmaxf(S[14], S[15]);
    float pmax = fmaxf(fmaxf(fmaxf(m01, m23), fmaxf(m45, m67)),
                       fmaxf(fmaxf(m89, mab), fmaxf(mcd, mef)));
    {
      auto sw = __builtin_amdgcn_permlane32_swap(uasf(pmax), uasf(pmax), false, false);
      pmax = fmaxf(fasu(sw[0]), fasu(sw[1]));
    }
    if (__any(pmax > mrun + 11.55f)) {      // defer-max (e^1 logit window)
      float mnew = fmaxf(mrun, pmax);
      float alpha = __ocml_exp2_f32(mrun - mnew);
      O0 *= alpha; O1 *= alpha; lrun *= alpha; mrun = mnew;
    }
    float p[16];
#pragma unroll
    for (int i = 0; i < 16; ++i) p[i] = __ocml_exp2_f32(S[i] - mrun);
    float s01 = p[0] + p[1],   s23 = p[2] + p[3];
    float s45 = p[4] + p[5],   s67 = p[6] + p[7];
    float s89 = p[8] + p[9],   sab = p[10] + p[11];
    float scd = p[12] + p[13], sef = p[14] + p[15];
    float ts = ((s01 + s23) + (s45 + s67)) + ((s89 + sab) + (scd + sef));
    {
      auto sw = __builtin_amdgcn_permlane32_swap(uasf(ts), uasf(ts), false, false);
      ts = fasu(sw[0]) + fasu(sw[1]);
    }
    lrun += ts;

    // --- O^T += V^T · P^T  (A = V^T frag from LDS, B = P^T in-register)
#define PV_CHUNK(kc_)                                                          \
    {                                                                          \
      const int b_ = 8 * (kc_);                                                \
      uint32_t X0, X1, Y0, Y1;                                                 \
      asm("v_cvt_pk_bf16_f32 %0, %1, %2" : "=v"(X0) : "v"(p[b_+0]), "v"(p[b_+1])); \
      asm("v_cvt_pk_bf16_f32 %0, %1, %2" : "=v"(X1) : "v"(p[b_+2]), "v"(p[b_+3])); \
      asm("v_cvt_pk_bf16_f32 %0, %1, %2" : "=v"(Y0) : "v"(p[b_+4]), "v"(p[b_+5])); \
      asm("v_cvt_pk_bf16_f32 %0, %1, %2" : "=v"(Y1) : "v"(p[b_+6]), "v"(p[b_+7])); \
      auto sw0 = __builtin_amdgcn_permlane32_swap(X0, Y0, false, false);       \
      auto sw1 = __builtin_amdgcn_permlane32_swap(X1, Y1, false, false);       \
      union { uint32_t u[4]; bf16x8 v; } cvb;                                  \
      cvb.u[0] = sw0[0]; cvb.u[1] = sw1[0];                                    \
      cvb.u[2] = sw0[1]; cvb.u[3] = sw1[1];                                    \
      bf16x8 Bp = cvb.v;                                                       \
      int vcol = 64 * cc + 32 * (kc_) + hioff;                                 \
      {                                                                        \
        bf16x8 Av = *(const bf16x8*)(cb + 32768 + lq * 256 + (vcol ^ swr));    \
        O0 = __builtin_amdgcn_mfma_f32_32x32x16_bf16(Av, Bp, O0, 0, 0, 0);     \
      }                                                                        \
      {                                                                        \
        bf16x8 Av = *(const bf16x8*)(cb + 32768 + (32 + lq) * 256 + (vcol ^ swr)); \
        O1 = __builtin_amdgcn_mfma_f32_32x32x16_bf16(Av, Bp, O1, 0, 0, 0);     \
      }                                                                        \
    }
    __builtin_amdgcn_s_setprio(1);
    PV_CHUNK(0)
    PV_CHUNK(1)
    __builtin_amdgcn_s_setprio(0);
#undef PV_CHUNK

    // tail: drain next tile's loads (flew during compute), then publish
    asm volatile("s_waitcnt vmcnt(0)" ::: "memory");
    __builtin_amdgcn_s_barrier();
    asm volatile("" ::: "memory");
    __builtin_amdgcn_sched_barrier(0);
  }

  // --- epilogue: 2-stage 4-way split-K merge, then direct f32x4 stores
  const int lsw = (l & 7) << 4;
#define DUMP(idx_)                                                             \
  {                                                                            \
    char* dd = smem + (idx_) * 8192 + l * 128;                                 \
    _Pragma("unroll")                                                          \
    for (int g = 0; g < 4; ++g) {                                              \
      f32x4 t0, t1;                                                            \
      _Pragma("unroll")                                                        \
      for (int j = 0; j < 4; ++j) { t0[j] = O0[4*g+j]; t1[j] = O1[4*g+j]; }    \
      *(f32x4*)(dd + ((g * 16) ^ lsw)) = t0;                                   \
      *(f32x4*)(dd + ((64 + g * 16) ^ lsw)) = t1;                              \
    }                                                                          \
    *(float*)(smem + MLB + (idx_) * 256 + lq * 8) = mrun;                      \
    *(float*)(smem + MLB + (idx_) * 256 + lq * 8 + 4) = lrun;                  \
  }
#define MERGE(idx_)                                                            \
  {                                                                            \
    const char* ds = smem + (idx_) * 8192 + l * 128;                           \
    float m1 = *(const float*)(smem + MLB + (idx_) * 256 + lq * 8);            \
    float l1 = *(const float*)(smem + MLB + (idx_) * 256 + lq * 8 + 4);        \
    float M = fmaxf(mrun, m1);                                                 \
    float a0 = __ocml_exp2_f32(mrun - M);                                      \
    float a1 = __ocml_exp2_f32(m1 - M);                                        \
    lrun = lrun * a0 + l1 * a1;                                                \
    mrun = M;                                                                  \
    _Pragma("unroll")                                                          \
    for (int g = 0; g < 4; ++g) {                                              \
      f32x4 o1a = *(const f32x4*)(ds + ((g * 16) ^ lsw));                      \
      f32x4 o1b = *(const f32x4*)(ds + ((64 + g * 16) ^ lsw));                 \
      _Pragma("unroll")                                                        \
      for (int j = 0; j < 4; ++j) {                                            \
        O0[4*g+j] = O0[4*g+j] * a0 + o1a[j] * a1;                              \
        O1[4*g+j] = O1[4*g+j] * a0 + o1b[j] * a1;                              \
      }                                                                        \
    }                                                                          \
  }
  if (cc & 1) DUMP(r * 2 + (cc >> 1));      // cc=1 -> idx 2r, cc=3 -> idx 2r+1
  __syncthreads();
  if (!(cc & 1)) MERGE(r * 2 + (cc >> 1));  // cc=0 takes cc=1, cc=2 takes cc=3
  __syncthreads();
  if (cc == 2) DUMP(r * 2 + 1);
  __syncthreads();
  if (cc == 0) {
    MERGE(r * 2 + 1);
    float inv = 1.0f / lrun;
    float* orow = out + ((size_t)bb * NT + (size_t)qt * QT + r * 32 + lq) * 64;
#pragma unroll
    for (int g = 0; g < 4; ++g) {
      int d0 = 8 * g + (hi ? 4 : 0);
      f32x4 s0, s1;
#pragma unroll
      for (int j = 0; j < 4; ++j) { s0[j] = O0[4*g+j] * inv; s1[j] = O1[4*g+j] * inv; }
      *(f32x4*)(orow + d0) = s0;
      *(f32x4*)(orow + d0 + 32) = s1;
    }
  }
#undef DUMP
#undef MERGE
#undef STAGE_TILE
}

extern "C" void kernel_launch(void* const* d_in, const int* in_sizes, int n_in,
                              void* d_out, int out_size, void* d_ws, size_t ws_size,
                              hipStream_t stream) {
  const float* x  = (const float*)d_in[0];
  const float* Wk = (const float*)d_in[1];
  const float* bk = (const float*)d_in[2];
  const float* Wq = (const float*)d_in[3];
  const float* bq = (const float*)d_in[4];
  const float* Wv = (const float*)d_in[5];
  const float* bv = (const float*)d_in[6];
  float* out = (float*)d_out;

  const size_t NE = (size_t)NBATCH * NT * 64;
  unsigned short* ws = (unsigned short*)d_ws;
  unsigned short* khi = ws;
  unsigned short* klo = ws + NE;
  unsigned short* qhi = ws + 2 * NE;
  unsigned short* qlo = ws + 3 * NE;
  unsigned short* vt  = ws + 4 * NE;
  unsigned short* wt_hi = ws + 5 * NE;
  unsigned short* wt_lo = wt_hi + 192 * 64;

  prep_w<<<dim3(3), dim3(256), 0, stream>>>(Wk, Wq, Wv, wt_hi, wt_lo);
  proj_kernel<<<dim3((NBATCH * NT) / 64), dim3(256), 0, stream>>>(
      x, wt_hi, wt_lo, bk, bq, bv, khi, klo, qhi, qlo, vt);
  attn_kernel<<<dim3(NBATCH * (NT / QT)), dim3(1024), 0, stream>>>(
      khi, klo, qhi, qlo, vt, out);
}